// Round 2
// 3471.946 us; speedup vs baseline: 1.4006x; 1.4006x over previous
//
#include <hip/hip_runtime.h>
#include <stdint.h>

#define T_TOT 512
#define B_TOT 1024
#define D_IN  128
#define HDIM  256
#define LN_EPS 1e-5f
#define OUT_Y_OFF ((size_t)T_TOT * B_TOT * HDIM)

typedef __attribute__((ext_vector_type(8))) short bf16x8;
typedef __attribute__((ext_vector_type(4))) float f32x4;
typedef __attribute__((ext_vector_type(4))) unsigned int u32x4;
typedef __attribute__((ext_vector_type(2))) unsigned int u32x2;

__device__ __forceinline__ unsigned short f2bf(float f) {
    union { float f; unsigned int u; } v; v.f = f;
    unsigned int r = v.u + 0x7FFFu + ((v.u >> 16) & 1u);   // RNE
    return (unsigned short)(r >> 16);
}
__device__ __forceinline__ float bflo(unsigned int u) {
    union { unsigned int u; float f; } v; v.u = u << 16; return v.f;
}
__device__ __forceinline__ float bfhi(unsigned int u) {
    union { unsigned int u; float f; } v; v.u = u & 0xFFFF0000u; return v.f;
}
// k' permutation for the recurrent contraction: k' = 64*wp + 4*c + cc  <->  j = 64*wp + 16*cc + c
__device__ __forceinline__ int jmap(int kp) {
    return ((kp >> 6) << 6) + ((kp & 3) << 4) + ((kp >> 2) & 15);
}
__device__ __forceinline__ float sigm(float x) {
    return __builtin_amdgcn_rcpf(1.f + __expf(-x));
}
__device__ __forceinline__ float tanh_f(float x) {
    return 1.f - 2.f * __builtin_amdgcn_rcpf(1.f + __expf(2.f * x));
}
template <int CTRL>
__device__ __forceinline__ float dppadd(float x) {
    int v = __builtin_amdgcn_update_dpp(0, __float_as_int(x), CTRL, 0xF, 0xF, true);
    return x + __int_as_float(v);
}
__device__ __forceinline__ float wave_sum64(float x) {
    x = dppadd<0x111>(x);  // row_shr:1
    x = dppadd<0x112>(x);  // row_shr:2
    x = dppadd<0x114>(x);  // row_shr:4
    x = dppadd<0x118>(x);  // row_shr:8  -> lane15/31/47/63 hold row sums
    x = dppadd<0x142>(x);  // row_bcast15
    x = dppadd<0x143>(x);  // row_bcast31 -> lane 63 has total
    return __int_as_float(__builtin_amdgcn_readlane(__float_as_int(x), 63));
}

// ---------------------------------------------------------------------------
// K1: gi = x @ W_ih^T + b_ih (+ b_hh for r,z gates), bf16, written in the
// MFMA C-fragment order K2 consumes: [bt][t_loc][w(8)][nt(6)][lane(64)][4 bf16]
// nt: 0,1 = r cols 32w+[0,16); 2,3 = z (+256); 4,5 = n (+512)
// (UNCHANGED: known-good.)
// ---------------------------------------------------------------------------
__global__ __launch_bounds__(512, 2) void gru_k1(
    const float* __restrict__ x, const float* __restrict__ W_ih,
    const float* __restrict__ b_ih, const float* __restrict__ b_hh,
    unsigned int* __restrict__ gi_ws, int t0c, int CH)
{
    __shared__ unsigned short xs[4][16][256];   // 4 t's, 16 rows, 128 k (bf16), XOR-swizzled 16B granules
    const int tid = threadIdx.x;
    const int bt = blockIdx.x;
    const int b0 = bt * 16;
    const int tbase = t0c + blockIdx.y * 4;

    // ---- stage x tile (fp32 -> bf16) ----
    {
        const int tt = tid >> 7;         // 0..3
        const int rem = tid & 127;
        const int r = rem >> 3;          // 0..15
        const int kq = rem & 7;          // k = 16*kq .. +15
        const float* xp = x + ((size_t)(tbase + tt) * B_TOT + b0 + r) * D_IN + 16 * kq;
        unsigned short us[16];
        #pragma unroll
        for (int i = 0; i < 16; ++i) us[i] = f2bf(xp[i]);
        char* base = (char*)&xs[tt][r][0];
        #pragma unroll
        for (int gph = 0; gph < 2; ++gph) {
            int pg = (2 * kq + gph) ^ (r & 7);
            u32x4 w;
            w.x = (unsigned int)us[8*gph+0] | ((unsigned int)us[8*gph+1] << 16);
            w.y = (unsigned int)us[8*gph+2] | ((unsigned int)us[8*gph+3] << 16);
            w.z = (unsigned int)us[8*gph+4] | ((unsigned int)us[8*gph+5] << 16);
            w.w = (unsigned int)us[8*gph+6] | ((unsigned int)us[8*gph+7] << 16);
            *(u32x4*)(base + pg * 16) = w;
        }
    }

    const int lane = tid & 63;
    const int w    = tid >> 6;   // 0..7
    const int n15  = lane & 15;
    const int lq   = lane >> 4;

    // ---- W_ih B-fragments (natural k order) + fused biases ----
    bf16x8 wih[6][4];
    float bias6[6];
    #pragma unroll
    for (int nt = 0; nt < 6; ++nt) {
        const int col = 256 * (nt >> 1) + 32 * w + 16 * (nt & 1) + n15;
        bias6[nt] = b_ih[col] + ((nt < 4) ? b_hh[col] : 0.f);
        #pragma unroll
        for (int kt = 0; kt < 4; ++kt) {
            bf16x8 f;
            #pragma unroll
            for (int jj = 0; jj < 8; ++jj)
                f[jj] = (short)f2bf(W_ih[(size_t)col * D_IN + kt * 32 + lq * 8 + jj]);
            wih[nt][kt] = f;
        }
    }
    __syncthreads();

    #pragma unroll
    for (int tt = 0; tt < 4; ++tt) {
        const char* abase = (const char*)&xs[tt][n15][0];
        bf16x8 a[4];
        #pragma unroll
        for (int kt = 0; kt < 4; ++kt) {
            int pg = (4 * kt + lq) ^ (n15 & 7);
            a[kt] = *(const bf16x8*)(abase + pg * 16);
        }
        f32x4 acc[6];
        #pragma unroll
        for (int nt = 0; nt < 6; ++nt) acc[nt] = (f32x4){0.f, 0.f, 0.f, 0.f};
        #pragma unroll
        for (int kt = 0; kt < 4; ++kt)
            #pragma unroll
            for (int nt = 0; nt < 6; ++nt)
                acc[nt] = __builtin_amdgcn_mfma_f32_16x16x32_bf16(a[kt], wih[nt][kt], acc[nt], 0, 0, 0);

        const int t_loc = blockIdx.y * 4 + tt;
        unsigned int* gp = gi_ws + ((size_t)(bt * CH + t_loc)) * 6144 + w * 768 + lane * 2;
        #pragma unroll
        for (int nt = 0; nt < 6; ++nt) {
            float a0 = acc[nt][0] + bias6[nt], a1 = acc[nt][1] + bias6[nt];
            float a2 = acc[nt][2] + bias6[nt], a3 = acc[nt][3] + bias6[nt];
            u32x2 pv;
            pv.x = (unsigned int)f2bf(a0) | ((unsigned int)f2bf(a1) << 16);
            pv.y = (unsigned int)f2bf(a2) | ((unsigned int)f2bf(a3) << 16);
            *(u32x2*)(gp + nt * 128) = pv;
        }
    }
}

// ---------------------------------------------------------------------------
// K2: the scan. 64 WGs x 256 threads (4 waves) — known-good structure.
// Wave w2 owns j-slice [64*w2, 64*w2+64). W_hh in 384 VGPRs as B-frags under
// k' permutation. One barrier per step; h state stays fp32 in registers.
// Changes vs known-good: (a) LN evicted to K3 — h_new (unmasked, bf16
// pair-packed) streamed coalesced to hn_ws instead of hn_lds+ln_store;
// (b) gi prefetch double-buffered one full step ahead.
// hn_ws layout: [t_loc][b][u=32*w2+2*c+s] u32; s=0: (j=64w2+c, +16),
// s=1: (j=64w2+32+c, +48).
// ---------------------------------------------------------------------------
__global__ __launch_bounds__(256, 1) void gru_k2(
    const unsigned int* __restrict__ gi_ws,
    const float* __restrict__ masks,
    const float* __restrict__ W_hh,
    const float* __restrict__ b_hh,
    const float* __restrict__ h_src,
    float* __restrict__ h_state,
    unsigned int* __restrict__ hn_ws,
    float* __restrict__ out,
    int t0c, int CH, int is_last)
{
    __shared__ unsigned short hm_lds[2][16 * 256];  // masked h, bf16, A-frag (k') layout, swizzled

    const int tid = threadIdx.x;
    const int bt = blockIdx.x;
    const int b0 = bt * 16;
    const int lane = tid & 63;
    const int w2 = tid >> 6;      // 0..3
    const int c = lane & 15;
    const int q = lane >> 4;

    // ---- W_hh B-fragments under k' permutation ----
    bf16x8 wh[3][4][8];
    #pragma unroll
    for (int g = 0; g < 3; ++g)
        #pragma unroll
        for (int cc = 0; cc < 4; ++cc) {
            const int col = 256 * g + 64 * w2 + 16 * cc + c;
            #pragma unroll
            for (int kt = 0; kt < 8; ++kt) {
                bf16x8 f;
                #pragma unroll
                for (int jj = 0; jj < 8; ++jj)
                    f[jj] = (short)f2bf(W_hh[(size_t)col * HDIM + jmap(32 * kt + 8 * q + jj)]);
                wh[g][cc][kt] = f;
            }
        }

    float bhn[4];
    #pragma unroll
    for (int cc = 0; cc < 4; ++cc) bhn[cc] = b_hh[512 + 64 * w2 + 16 * cc + c];

    // ---- pre-loop: stage hm for first step; init per-lane masked h regs ----
    {
        const int row = tid >> 4;
        const int cs = tid & 15;
        const float m0 = masks[(size_t)t0c * B_TOT + b0 + row];
        unsigned short us[16];
        #pragma unroll
        for (int e = 0; e < 16; ++e)
            us[e] = f2bf(h_src[(size_t)(b0 + row) * HDIM + jmap(16 * cs + e)] * m0);
        char* base = (char*)&hm_lds[0][0] + row * 512;
        #pragma unroll
        for (int gph = 0; gph < 2; ++gph) {
            int pg = (2 * cs + gph) ^ (row & 7);
            u32x4 wv;
            wv.x = (unsigned int)us[8*gph+0] | ((unsigned int)us[8*gph+1] << 16);
            wv.y = (unsigned int)us[8*gph+2] | ((unsigned int)us[8*gph+3] << 16);
            wv.z = (unsigned int)us[8*gph+4] | ((unsigned int)us[8*gph+5] << 16);
            wv.w = (unsigned int)us[8*gph+6] | ((unsigned int)us[8*gph+7] << 16);
            *(u32x4*)(base + pg * 16) = wv;
        }
    }
    unsigned int hmreg[4][2];   // masked h, bf16-packed pairs [row i][cc-pair]
    #pragma unroll
    for (int i = 0; i < 4; ++i) {
        const int row = 4 * q + i;
        const float m0 = masks[(size_t)t0c * B_TOT + b0 + row];
        float h0[4];
        #pragma unroll
        for (int cc = 0; cc < 4; ++cc)
            h0[cc] = h_src[(size_t)(b0 + row) * HDIM + 64 * w2 + 16 * cc + c] * m0;
        hmreg[i][0] = (unsigned int)f2bf(h0[0]) | ((unsigned int)f2bf(h0[1]) << 16);
        hmreg[i][1] = (unsigned int)f2bf(h0[2]) | ((unsigned int)f2bf(h0[3]) << 16);
    }
    __syncthreads();

    const u32x2* gbase = (const u32x2*)gi_ws + (size_t)bt * CH * 3072 + (size_t)w2 * 768 + lane;

    // gi double-buffer: current step's fragments live in gic; next step's
    // loads are issued at the top of each step (register loads survive the
    // barrier — full-step latency cover).
    u32x2 gic[3][4];
    #pragma unroll
    for (int g = 0; g < 3; ++g)
        #pragma unroll
        for (int cc = 0; cc < 4; ++cc)
            gic[g][cc] = gbase[(cc >> 1) * 384 + g * 128 + (cc & 1) * 64];

    for (int t = 0; t < CH; ++t) {
        const int tg = t0c + t;

        // prefetch gi for t+1 (clamped; last-step reload is harmless/unused)
        u32x2 gin[3][4];
        {
            const int tp = (t + 1 < CH) ? (t + 1) : (CH - 1);
            const u32x2* gp = gbase + (size_t)tp * 3072;
            #pragma unroll
            for (int g = 0; g < 3; ++g)
                #pragma unroll
                for (int cc = 0; cc < 4; ++cc)
                    gin[g][cc] = gp[(cc >> 1) * 384 + g * 128 + (cc & 1) * 64];
        }
        // prefetch masks for t+1 (used when staging hm for next step)
        const int tn = (tg + 1 < T_TOT) ? (tg + 1) : (T_TOT - 1);
        float mnext[4];
        #pragma unroll
        for (int i = 0; i < 4; ++i)
            mnext[i] = masks[(size_t)tn * B_TOT + b0 + 4 * q + i];

        // A-frags + MFMA (gh = hm @ W_hh^T, no bias)
        f32x4 acc[3][4];
        #pragma unroll
        for (int g = 0; g < 3; ++g)
            #pragma unroll
            for (int cc = 0; cc < 4; ++cc)
                acc[g][cc] = (f32x4){0.f, 0.f, 0.f, 0.f};

        const char* hmb = (const char*)&hm_lds[t & 1][0] + (size_t)c * 512;
        bf16x8 acur = *(const bf16x8*)(hmb + ((q ^ (c & 7)) * 16));
        #pragma unroll
        for (int kt = 0; kt < 8; ++kt) {
            bf16x8 anext = acur;
            if (kt < 7)
                anext = *(const bf16x8*)(hmb + (((4 * (kt + 1) + q) ^ (c & 7)) * 16));
            #pragma unroll
            for (int g = 0; g < 3; ++g)
                #pragma unroll
                for (int cc = 0; cc < 4; ++cc)
                    acc[g][cc] = __builtin_amdgcn_mfma_f32_16x16x32_bf16(acur, wh[g][cc][kt], acc[g][cc], 0, 0, 0);
            acur = anext;
        }

        // gates, h update, staging
        unsigned short* hmw = &hm_lds[(t + 1) & 1][0];
        #pragma unroll
        for (int i = 0; i < 4; ++i) {
            const int row = 4 * q + i;
            float hn4[4];
            #pragma unroll
            for (int cc = 0; cc < 4; ++cc) {
                unsigned int hp = hmreg[i][cc >> 1];
                float hmv = (cc & 1) ? bfhi(hp) : bflo(hp);
                unsigned int grw = (i & 2) ? gic[0][cc].y : gic[0][cc].x;
                unsigned int gzw = (i & 2) ? gic[1][cc].y : gic[1][cc].x;
                unsigned int gnw = (i & 2) ? gic[2][cc].y : gic[2][cc].x;
                float girv = (i & 1) ? bfhi(grw) : bflo(grw);
                float gizv = (i & 1) ? bfhi(gzw) : bflo(gzw);
                float ginv = (i & 1) ? bfhi(gnw) : bflo(gnw);
                float r = sigm(acc[0][cc][i] + girv);
                float z = sigm(acc[1][cc][i] + gizv);
                float n = tanh_f(ginv + r * (acc[2][cc][i] + bhn[cc]));
                hn4[cc] = n + z * (hmv - n);
            }
            // stream unmasked h_new (bf16 pairs) to workspace for K3's LN
            {
                unsigned int p0 = (unsigned int)f2bf(hn4[0]) | ((unsigned int)f2bf(hn4[1]) << 16);
                unsigned int p1 = (unsigned int)f2bf(hn4[2]) | ((unsigned int)f2bf(hn4[3]) << 16);
                *(u32x2*)(hn_ws + ((size_t)t * B_TOT + b0 + row) * 128 + 32 * w2 + 2 * c) =
                    (u32x2){p0, p1};
            }
            // masked h for next step: registers + LDS (k'-layout, swizzled)
            float hm0 = hn4[0] * mnext[i], hm1 = hn4[1] * mnext[i];
            float hm2 = hn4[2] * mnext[i], hm3 = hn4[3] * mnext[i];
            unsigned int m0p = (unsigned int)f2bf(hm0) | ((unsigned int)f2bf(hm1) << 16);
            unsigned int m1p = (unsigned int)f2bf(hm2) | ((unsigned int)f2bf(hm3) << 16);
            hmreg[i][0] = m0p; hmreg[i][1] = m1p;
            const int pg = ((8 * w2 + (c >> 1)) ^ (row & 7));
            const int boff = row * 512 + pg * 16 + (c & 1) * 8;
            *(u32x2*)((char*)hmw + boff) = (u32x2){m0p, m1p};
            if (t == CH - 1) {
                float* hs = h_state + (size_t)(b0 + row) * HDIM + 64 * w2 + c;
                #pragma unroll
                for (int cc = 0; cc < 4; ++cc) hs[16 * cc] = hn4[cc];
                if (is_last) {
                    float* ho = out + OUT_Y_OFF + (size_t)(b0 + row) * HDIM + 64 * w2 + c;
                    #pragma unroll
                    for (int cc = 0; cc < 4; ++cc) ho[16 * cc] = hn4[cc];
                }
            }
        }
        #pragma unroll
        for (int g = 0; g < 3; ++g)
            #pragma unroll
            for (int cc = 0; cc < 4; ++cc)
                gic[g][cc] = gin[g][cc];
        __syncthreads();
    }
}

// ---------------------------------------------------------------------------
// K3: fully-parallel LayerNorm + y store (memory-bound, all CUs).
// One wave per (t,b) row. hn_ws u32 index u = 32*w2 + 2*c + s; lane reads
// u = 2*lane, 2*lane+1  ->  holds j0, j0+16, j0+32, j0+48 with
// j0 = 64*(lane>>4) + (lane&15). Permutation is irrelevant for the stats.
// ---------------------------------------------------------------------------
__global__ __launch_bounds__(256, 4) void gru_k3(
    const unsigned int* __restrict__ hn_ws,
    const float* __restrict__ ln_w, const float* __restrict__ ln_b,
    float* __restrict__ out, int t0c)
{
    const int lane = threadIdx.x & 63;
    const size_t R = (size_t)blockIdx.x * 4 + (threadIdx.x >> 6);   // t_loc*B + b

    u32x2 v = *((const u32x2*)(hn_ws + R * 128) + lane);
    float x0 = bflo(v.x), x1 = bfhi(v.x), x2 = bflo(v.y), x3 = bfhi(v.y);
    float s  = (x0 + x1) + (x2 + x3);
    float s2 = (x0 * x0 + x1 * x1) + (x2 * x2 + x3 * x3);
    float ts  = wave_sum64(s);
    float ts2 = wave_sum64(s2);
    float mu = ts * (1.f / 256.f);
    float var = ts2 * (1.f / 256.f) - mu * mu;
    float rs = __builtin_amdgcn_rsqf(var + LN_EPS);

    const int j0 = 64 * (lane >> 4) + (lane & 15);
    float* op = out + ((size_t)t0c * B_TOT + R) * HDIM;
    op[j0]      = (x0 - mu) * rs * ln_w[j0]      + ln_b[j0];
    op[j0 + 16] = (x1 - mu) * rs * ln_w[j0 + 16] + ln_b[j0 + 16];
    op[j0 + 32] = (x2 - mu) * rs * ln_w[j0 + 32] + ln_b[j0 + 32];
    op[j0 + 48] = (x3 - mu) * rs * ln_w[j0 + 48] + ln_b[j0 + 48];
}

extern "C" void kernel_launch(void* const* d_in, const int* in_sizes, int n_in,
                              void* d_out, int out_size, void* d_ws, size_t ws_size,
                              hipStream_t stream)
{
    const float* x     = (const float*)d_in[0];
    const float* rnn   = (const float*)d_in[1];
    const float* masks = (const float*)d_in[2];
    const float* W_ih  = (const float*)d_in[3];
    const float* W_hh  = (const float*)d_in[4];
    const float* b_ih  = (const float*)d_in[5];
    const float* b_hh  = (const float*)d_in[6];
    const float* ln_w  = (const float*)d_in[7];
    const float* ln_b  = (const float*)d_in[8];
    float* out = (float*)d_out;

    // ws: gi (64*CH*24576 B) | hn (CH*B*512 B) | h_state (B*H*4 B)
    int CH = 64;
    while (CH > 8) {
        size_t need = (size_t)CH * (64 * 24576 + (size_t)B_TOT * 512) + (size_t)B_TOT * HDIM * 4;
        if (need <= ws_size) break;
        CH >>= 1;
    }
    unsigned int* gi_ws = (unsigned int*)d_ws;
    unsigned int* hn_ws = (unsigned int*)((char*)d_ws + (size_t)64 * CH * 24576);
    float* h_state = (float*)((char*)hn_ws + (size_t)CH * B_TOT * 512);

    const int nch = T_TOT / CH;
    for (int cidx = 0; cidx < nch; ++cidx) {
        const int t0c = cidx * CH;
        gru_k1<<<dim3(64, CH / 4), 512, 0, stream>>>(x, W_ih, b_ih, b_hh, gi_ws, t0c, CH);
        const float* hsrc = (cidx == 0) ? rnn : h_state;
        gru_k2<<<dim3(64), 256, 0, stream>>>(gi_ws, masks, W_hh, b_hh,
                                             hsrc, h_state, hn_ws, out, t0c, CH,
                                             (cidx == nch - 1) ? 1 : 0);
        gru_k3<<<dim3(CH * (B_TOT / 4)), 256, 0, stream>>>(hn_ws, ln_w, ln_b, out, t0c);
    }
}